// Round 9
// baseline (134.849 us; speedup 1.0000x reference)
//
#include <hip/hip_runtime.h>
#include <stdint.h>

// MetricLoss: B=1024, M=32, F=256, K_GRP=4
// out[0] = (1/1536) * sum_{same-group pairs i<j, m} ||x_i,m - x_j,m||^2
// out[1] = (1/522240) * sum_{g_i<g_j, m} relu(1 - ||x_i,m - x_j,m||^2)
//
// R9: k_heter = BK=64 double-buffered pipeline, 68 KB LDS -> 2 blocks/CU
// (R8 counters showed 1 blk/CU latency-bound: Occ 8.6%, Mfma 14%, VALU 17%).
// k_final folded into k_heter via done-counter (ctr zeroed by k_fused).
//
// ws layout:
//   [0,        16 MiB)   : xb  bf16 [32][1024][256]
//   [16 MiB,  +128 KiB)  : sq  f32  [32][1024]
//   [+32 KiB]            : homo_part  f32 [8192]
//   [+4.5 KiB]           : heter_part f32 [1152]
//   [+4 B]               : ctr u32 (done counter; reset by k_fused)

typedef __attribute__((ext_vector_type(4))) float f32x4;
typedef __attribute__((ext_vector_type(8))) short bf16x8;

#define XB_OFF    0u
#define SQ_OFF    16777216u
#define HOMO_OFF  16908288u   // 8192 floats
#define HETER_OFF 16941056u   // 1152 floats
#define CTR_OFF   16945664u   // 1 u32

#define AS1 __attribute__((address_space(1)))
#define AS3 __attribute__((address_space(3)))

__device__ __forceinline__ void async16(const void* g, void* l) {
  __builtin_amdgcn_global_load_lds((const AS1 unsigned int*)(uintptr_t)g,
                                   (AS3 unsigned int*)(uintptr_t)l, 16, 0, 0);
}

__device__ __forceinline__ unsigned short f2bf(float f) {
  union { float f; unsigned u; } v; v.f = f;
  return (unsigned short)((v.u + 0x7fffu + ((v.u >> 16) & 1u)) >> 16);
}

// ---- Kernel 1 (fused convert + homo) — unchanged except ctr reset
__global__ __launch_bounds__(256) void k_fused(const float* __restrict__ x,
                                               unsigned short* __restrict__ xb,
                                               float* __restrict__ sq,
                                               float* __restrict__ homo_part,
                                               unsigned* __restrict__ ctr) {
  if (blockIdx.x == 0 && threadIdx.x == 0) ctr[0] = 0;   // reset done-counter
  const int task = blockIdx.x * 4 + (threadIdx.x >> 6);  // task = g*32 + m
  const int lane = threadIdx.x & 63;
  const int g = task >> 5;
  const int m = task & 31;

  const float* base = x + ((size_t)(g * 4) * 32 + m) * 256 + lane * 4;
  float4 v[4];
  float sqv[4];
  #pragma unroll
  for (int a = 0; a < 4; ++a) {
    v[a] = *(const float4*)(base + a * 8192);
    float s = v[a].x * v[a].x + v[a].y * v[a].y + v[a].z * v[a].z + v[a].w * v[a].w;
    #pragma unroll
    for (int off = 32; off; off >>= 1) s += __shfl_xor(s, off, 64);
    sqv[a] = s;
    const int i = g * 4 + a;
    if (lane == 0) sq[m * 1024 + i] = s;
    ushort4 o;
    o.x = f2bf(v[a].x); o.y = f2bf(v[a].y); o.z = f2bf(v[a].z); o.w = f2bf(v[a].w);
    *(ushort4*)(xb + ((size_t)(m * 1024 + i)) * 256 + lane * 4) = o;
  }
  const float sx = v[0].x + v[1].x + v[2].x + v[3].x;
  const float sy = v[0].y + v[1].y + v[2].y + v[3].y;
  const float sz = v[0].z + v[1].z + v[2].z + v[3].z;
  const float sw = v[0].w + v[1].w + v[2].w + v[3].w;
  float s = sx * sx + sy * sy + sz * sz + sw * sw;
  #pragma unroll
  for (int off = 32; off; off >>= 1) s += __shfl_xor(s, off, 64);
  if (lane == 0)
    homo_part[task] = 4.f * (sqv[0] + sqv[1] + sqv[2] + sqv[3]) - s;
}

// Stage one 16 KB panel-step (128 rows x 64 k) into an LDS buffer.
// Row-XOR chunk swizzle within the 8 chunks/row: LDS(row,c) = G(row, c^(row&7)).
__device__ __forceinline__ void stage_panel(const unsigned short* __restrict__ X,
                                            int k0, unsigned short* buf, int tid) {
  #pragma unroll
  for (int i = 0; i < 4; ++i) {
    const int ch = i * 256 + tid;            // 1024 chunks of 16B
    const int row = ch >> 3;
    const int gc = (ch & 7) ^ (row & 7);
    async16(X + (size_t)row * 256 + k0 + gc * 8, (char*)buf + ch * 16);
  }
}

// ---- Kernel 2: heter loss, BK=64 double-buffered, 2 blocks/CU, fused final.
__global__ __launch_bounds__(256, 2) void k_heter(const unsigned short* __restrict__ xb,
                                                  const float* __restrict__ sq,
                                                  const float* __restrict__ homo_part,
                                                  float* __restrict__ heter_part,
                                                  unsigned* __restrict__ ctr,
                                                  float* __restrict__ out) {
  const int d = blockIdx.x;                  // 1152 = 8 * 144
  const int w = (d & 7) * 144 + (d >> 3);    // XCD chunk map (bijective)
  const int m = w / 36;
  int t0 = w - m * 36, r = 0;                // triangle decode: (r,c), c>=r
  while (t0 >= 8 - r) { t0 -= 8 - r; ++r; }
  const int cb = r + t0;
  const bool diag = (cb == r);

  __shared__ __align__(16) unsigned short A0[8192], A1[8192];  // 16 KB each
  __shared__ __align__(16) unsigned short B0[8192], B1[8192];
  __shared__ __align__(16) float sql[1024];                    // 4 KB sq row
  __shared__ float part[4];
  __shared__ int lastflag;

  const int tid = threadIdx.x;
  const int lane = tid & 63;
  const int wid = tid >> 6;
  const int wr = wid >> 1, wc = wid & 1;     // 2x2 waves, each 64x64 output
  const int fr = lane & 15;
  const int kg = lane >> 4;

  const unsigned short* Xa = xb + ((size_t)m * 1024 + r  * 128) * 256;
  const unsigned short* Xb = xb + ((size_t)m * 1024 + cb * 128) * 256;

  // prologue: sq row + steps 0,1 of both panels
  async16(sq + m * 1024 + tid * 4, (char*)sql + tid * 16);
  stage_panel(Xa, 0, A0, tid);
  if (!diag) stage_panel(Xb, 0, B0, tid);
  stage_panel(Xa, 64, A1, tid);
  if (!diag) stage_panel(Xb, 64, B1, tid);

  f32x4 acc[4][4] = {};

  #pragma unroll
  for (int s = 0; s < 4; ++s) {
    // counted wait: step-s buffers complete; step-(s+1) loads stay in flight
    if (s < 3) {
      if (diag) asm volatile("s_waitcnt vmcnt(4)" ::: "memory");
      else      asm volatile("s_waitcnt vmcnt(8)" ::: "memory");
    } else {
      asm volatile("s_waitcnt vmcnt(0)" ::: "memory");
    }
    __builtin_amdgcn_s_barrier();
    asm volatile("" ::: "memory");

    const unsigned short* lA = (s & 1) ? A1 : A0;
    const unsigned short* lB = diag ? lA : ((s & 1) ? B1 : B0);
    #pragma unroll
    for (int kk = 0; kk < 2; ++kk) {
      bf16x8 af[4], bv[4];
      #pragma unroll
      for (int q = 0; q < 4; ++q) {
        const int ra = wr * 64 + q * 16 + fr;
        af[q] = *(const bf16x8*)(lA + ra * 64 + (((kk << 2) + kg) ^ (ra & 7)) * 8);
        const int rb = wc * 64 + q * 16 + fr;
        bv[q] = *(const bf16x8*)(lB + rb * 64 + (((kk << 2) + kg) ^ (rb & 7)) * 8);
      }
      #pragma unroll
      for (int ai = 0; ai < 4; ++ai)
        #pragma unroll
        for (int bj = 0; bj < 4; ++bj)
          acc[ai][bj] = __builtin_amdgcn_mfma_f32_16x16x32_bf16(af[ai], bv[bj],
                                                                acc[ai][bj], 0, 0, 0);
    }

    asm volatile("" ::: "memory");
    __builtin_amdgcn_s_barrier();            // all waves done reading step-s bufs
    asm volatile("" ::: "memory");
    if (s + 2 < 4) {                         // refill freed buffers with step s+2
      stage_panel(Xa, (s + 2) * 64, (s & 1) ? A1 : A0, tid);
      if (!diag) stage_panel(Xb, (s + 2) * 64, (s & 1) ? B1 : B0, tid);
    }
  }

  // epilogue: relu(1 - (sq_i + sq_j - 2*dot)), strict group mask, reduce
  const int ibase = r  * 128 + wr * 64;
  const int jbase = cb * 128 + wc * 64;
  float sqi[4][4];
  #pragma unroll
  for (int ai = 0; ai < 4; ++ai)
    #pragma unroll
    for (int rg = 0; rg < 4; ++rg)
      sqi[ai][rg] = sql[ibase + ai * 16 + kg * 4 + rg];

  float local = 0.f;
  #pragma unroll
  for (int bj = 0; bj < 4; ++bj) {
    const int j = jbase + bj * 16 + fr;      // C/D: col = lane&15
    const float sqj = sql[j];
    const int gj = j >> 2;
    #pragma unroll
    for (int ai = 0; ai < 4; ++ai)
      #pragma unroll
      for (int rg = 0; rg < 4; ++rg) {
        const int i = ibase + ai * 16 + kg * 4 + rg;  // row = (lane>>4)*4 + reg
        const float dd = sqi[ai][rg] + sqj - 2.f * acc[ai][bj][rg];
        const float v = 1.f - dd;
        if (v > 0.f && gj > (i >> 2)) local += v;
      }
  }
  #pragma unroll
  for (int off = 32; off; off >>= 1) local += __shfl_xor(local, off, 64);
  if (lane == 0) part[wid] = local;
  __syncthreads();
  if (tid == 0) heter_part[w] = part[0] + part[1] + part[2] + part[3];

  // fused final: last block reduces all partials and writes out
  __threadfence();
  __syncthreads();
  if (tid == 0) {
    const unsigned prev = __hip_atomic_fetch_add(&ctr[0], 1u, __ATOMIC_ACQ_REL,
                                                 __HIP_MEMORY_SCOPE_AGENT);
    lastflag = (prev == 1151u);
  }
  __syncthreads();
  if (!lastflag) return;
  __threadfence();

  float h = 0.f;
  for (int i = tid; i < 8192; i += 256) h += homo_part[i];
  #pragma unroll
  for (int off = 32; off; off >>= 1) h += __shfl_xor(h, off, 64);
  float e = 0.f;
  for (int i = tid; i < 1152; i += 256) e += heter_part[i];
  #pragma unroll
  for (int off = 32; off; off >>= 1) e += __shfl_xor(e, off, 64);
  __syncthreads();
  if (lane == 0) part[wid] = h;
  __syncthreads();
  if (tid == 0) out[0] = (part[0] + part[1] + part[2] + part[3]) * (1.0f / 1536.0f);
  __syncthreads();
  if (lane == 0) part[wid] = e;
  __syncthreads();
  if (tid == 0) out[1] = (part[0] + part[1] + part[2] + part[3]) * (1.0f / 522240.0f);
}

extern "C" void kernel_launch(void* const* d_in, const int* in_sizes, int n_in,
                              void* d_out, int out_size, void* d_ws, size_t ws_size,
                              hipStream_t stream) {
  const float* x = (const float*)d_in[0];
  float* out = (float*)d_out;
  char* ws = (char*)d_ws;
  unsigned short* xb = (unsigned short*)(ws + XB_OFF);
  float* sq         = (float*)(ws + SQ_OFF);
  float* homo_part  = (float*)(ws + HOMO_OFF);
  float* heter_part = (float*)(ws + HETER_OFF);
  unsigned* ctr     = (unsigned*)(ws + CTR_OFF);

  k_fused<<<2048, 256, 0, stream>>>(x, xb, sq, homo_part, ctr);
  k_heter<<<1152, 256, 0, stream>>>(xb, sq, homo_part, heter_part, ctr, out);
}

// Round 10
// 38.432 us; speedup vs baseline: 3.5088x; 3.5088x over previous
//
#include <hip/hip_runtime.h>
#include <stdint.h>

// MetricLoss: B=1024, M=32, F=256, K_GRP=4
// out[0] = (1/1536) * sum_{same-group pairs i<j, m} ||x_i,m - x_j,m||^2
// out[1] = (1/522240) * sum_{g_i<g_j, m} relu(1 - ||x_i,m - x_j,m||^2)
//
// R10: R9's BK=64 double-buffered k_heter (2 blocks/CU) WITHOUT the fused
// final -- R9's 127us was attributed to per-block __threadfence + agent-scope
// atomics (L2 writeback/invalidate storms across 8 XCDs killing the
// L2-resident xb panels). No device-scope sync anywhere in the hot path.
//
// ws layout:
//   [0,        16 MiB)   : xb  bf16 [32][1024][256]
//   [16 MiB,  +128 KiB)  : sq  f32  [32][1024]
//   [+32 KiB]            : homo_part  f32 [8192]
//   [+4.5 KiB]           : heter_part f32 [1152]

typedef __attribute__((ext_vector_type(4))) float f32x4;
typedef __attribute__((ext_vector_type(8))) short bf16x8;

#define XB_OFF    0u
#define SQ_OFF    16777216u
#define HOMO_OFF  16908288u   // 8192 floats
#define HETER_OFF 16941056u   // 1152 floats

#define AS1 __attribute__((address_space(1)))
#define AS3 __attribute__((address_space(3)))

__device__ __forceinline__ void async16(const void* g, void* l) {
  __builtin_amdgcn_global_load_lds((const AS1 unsigned int*)(uintptr_t)g,
                                   (AS3 unsigned int*)(uintptr_t)l, 16, 0, 0);
}

__device__ __forceinline__ unsigned short f2bf(float f) {
  union { float f; unsigned u; } v; v.f = f;
  return (unsigned short)((v.u + 0x7fffu + ((v.u >> 16) & 1u)) >> 16);
}

// ---- Kernel 1 (fused convert + homo) — unchanged
__global__ __launch_bounds__(256) void k_fused(const float* __restrict__ x,
                                               unsigned short* __restrict__ xb,
                                               float* __restrict__ sq,
                                               float* __restrict__ homo_part) {
  const int task = blockIdx.x * 4 + (threadIdx.x >> 6);  // task = g*32 + m
  const int lane = threadIdx.x & 63;
  const int g = task >> 5;
  const int m = task & 31;

  const float* base = x + ((size_t)(g * 4) * 32 + m) * 256 + lane * 4;
  float4 v[4];
  float sqv[4];
  #pragma unroll
  for (int a = 0; a < 4; ++a) {
    v[a] = *(const float4*)(base + a * 8192);
    float s = v[a].x * v[a].x + v[a].y * v[a].y + v[a].z * v[a].z + v[a].w * v[a].w;
    #pragma unroll
    for (int off = 32; off; off >>= 1) s += __shfl_xor(s, off, 64);
    sqv[a] = s;
    const int i = g * 4 + a;
    if (lane == 0) sq[m * 1024 + i] = s;
    ushort4 o;
    o.x = f2bf(v[a].x); o.y = f2bf(v[a].y); o.z = f2bf(v[a].z); o.w = f2bf(v[a].w);
    *(ushort4*)(xb + ((size_t)(m * 1024 + i)) * 256 + lane * 4) = o;
  }
  const float sx = v[0].x + v[1].x + v[2].x + v[3].x;
  const float sy = v[0].y + v[1].y + v[2].y + v[3].y;
  const float sz = v[0].z + v[1].z + v[2].z + v[3].z;
  const float sw = v[0].w + v[1].w + v[2].w + v[3].w;
  float s = sx * sx + sy * sy + sz * sz + sw * sw;
  #pragma unroll
  for (int off = 32; off; off >>= 1) s += __shfl_xor(s, off, 64);
  if (lane == 0)
    homo_part[task] = 4.f * (sqv[0] + sqv[1] + sqv[2] + sqv[3]) - s;
}

// Stage one 16 KB panel-step (128 rows x 64 k) into an LDS buffer.
// Row-XOR chunk swizzle within the 8 chunks/row: LDS(row,c) = G(row, c^(row&7)).
__device__ __forceinline__ void stage_panel(const unsigned short* __restrict__ X,
                                            int k0, unsigned short* buf, int tid) {
  #pragma unroll
  for (int i = 0; i < 4; ++i) {
    const int ch = i * 256 + tid;            // 1024 chunks of 16B
    const int row = ch >> 3;
    const int gc = (ch & 7) ^ (row & 7);
    async16(X + (size_t)row * 256 + k0 + gc * 8, (char*)buf + ch * 16);
  }
}

// ---- Kernel 2: heter loss, BK=64 double-buffered, 2 blocks/CU.
__global__ __launch_bounds__(256, 2) void k_heter(const unsigned short* __restrict__ xb,
                                                  const float* __restrict__ sq,
                                                  float* __restrict__ heter_part) {
  const int d = blockIdx.x;                  // 1152 = 8 * 144
  const int w = (d & 7) * 144 + (d >> 3);    // XCD chunk map (bijective)
  const int m = w / 36;
  int t0 = w - m * 36, r = 0;                // triangle decode: (r,c), c>=r
  while (t0 >= 8 - r) { t0 -= 8 - r; ++r; }
  const int cb = r + t0;
  const bool diag = (cb == r);

  __shared__ __align__(16) unsigned short A0[8192], A1[8192];  // 16 KB each
  __shared__ __align__(16) unsigned short B0[8192], B1[8192];
  __shared__ __align__(16) float sql[1024];                    // 4 KB sq row
  __shared__ float part[4];

  const int tid = threadIdx.x;
  const int lane = tid & 63;
  const int wid = tid >> 6;
  const int wr = wid >> 1, wc = wid & 1;     // 2x2 waves, each 64x64 output
  const int fr = lane & 15;
  const int kg = lane >> 4;

  const unsigned short* Xa = xb + ((size_t)m * 1024 + r  * 128) * 256;
  const unsigned short* Xb = xb + ((size_t)m * 1024 + cb * 128) * 256;

  // prologue: sq row + steps 0,1 of both panels
  async16(sq + m * 1024 + tid * 4, (char*)sql + tid * 16);
  stage_panel(Xa, 0, A0, tid);
  if (!diag) stage_panel(Xb, 0, B0, tid);
  stage_panel(Xa, 64, A1, tid);
  if (!diag) stage_panel(Xb, 64, B1, tid);

  f32x4 acc[4][4] = {};

  #pragma unroll
  for (int s = 0; s < 4; ++s) {
    // counted wait: step-s buffers complete; step-(s+1) loads stay in flight
    if (s < 3) {
      if (diag) asm volatile("s_waitcnt vmcnt(4)" ::: "memory");
      else      asm volatile("s_waitcnt vmcnt(8)" ::: "memory");
    } else {
      asm volatile("s_waitcnt vmcnt(0)" ::: "memory");
    }
    __builtin_amdgcn_s_barrier();
    asm volatile("" ::: "memory");

    const unsigned short* lA = (s & 1) ? A1 : A0;
    const unsigned short* lB = diag ? lA : ((s & 1) ? B1 : B0);
    #pragma unroll
    for (int kk = 0; kk < 2; ++kk) {
      bf16x8 af[4], bv[4];
      #pragma unroll
      for (int q = 0; q < 4; ++q) {
        const int ra = wr * 64 + q * 16 + fr;
        af[q] = *(const bf16x8*)(lA + ra * 64 + (((kk << 2) + kg) ^ (ra & 7)) * 8);
        const int rb = wc * 64 + q * 16 + fr;
        bv[q] = *(const bf16x8*)(lB + rb * 64 + (((kk << 2) + kg) ^ (rb & 7)) * 8);
      }
      #pragma unroll
      for (int ai = 0; ai < 4; ++ai)
        #pragma unroll
        for (int bj = 0; bj < 4; ++bj)
          acc[ai][bj] = __builtin_amdgcn_mfma_f32_16x16x32_bf16(af[ai], bv[bj],
                                                                acc[ai][bj], 0, 0, 0);
    }

    asm volatile("" ::: "memory");
    __builtin_amdgcn_s_barrier();            // all waves done reading step-s bufs
    asm volatile("" ::: "memory");
    if (s + 2 < 4) {                         // refill freed buffers with step s+2
      stage_panel(Xa, (s + 2) * 64, (s & 1) ? A1 : A0, tid);
      if (!diag) stage_panel(Xb, (s + 2) * 64, (s & 1) ? B1 : B0, tid);
    }
  }

  // epilogue: relu(1 - (sq_i + sq_j - 2*dot)), strict group mask, reduce
  const int ibase = r  * 128 + wr * 64;
  const int jbase = cb * 128 + wc * 64;
  float sqi[4][4];
  #pragma unroll
  for (int ai = 0; ai < 4; ++ai)
    #pragma unroll
    for (int rg = 0; rg < 4; ++rg)
      sqi[ai][rg] = sql[ibase + ai * 16 + kg * 4 + rg];

  float local = 0.f;
  #pragma unroll
  for (int bj = 0; bj < 4; ++bj) {
    const int j = jbase + bj * 16 + fr;      // C/D: col = lane&15
    const float sqj = sql[j];
    const int gj = j >> 2;
    #pragma unroll
    for (int ai = 0; ai < 4; ++ai)
      #pragma unroll
      for (int rg = 0; rg < 4; ++rg) {
        const int i = ibase + ai * 16 + kg * 4 + rg;  // row = (lane>>4)*4 + reg
        const float dd = sqi[ai][rg] + sqj - 2.f * acc[ai][bj][rg];
        const float v = 1.f - dd;
        if (v > 0.f && gj > (i >> 2)) local += v;
      }
  }
  #pragma unroll
  for (int off = 32; off; off >>= 1) local += __shfl_xor(local, off, 64);
  if (lane == 0) part[wid] = local;
  __syncthreads();
  if (tid == 0) heter_part[w] = part[0] + part[1] + part[2] + part[3];
}

// ---- Kernel 3: final reduction of partials + scaling (single block)
__global__ __launch_bounds__(256) void k_final(const float* __restrict__ homo_part,
                                               const float* __restrict__ heter_part,
                                               float* __restrict__ out) {
  __shared__ float red[8];
  const int tid = threadIdx.x;
  const int lane = tid & 63;
  const int wid = tid >> 6;

  float h = 0.f;
  for (int i = tid; i < 8192; i += 256) h += homo_part[i];
  #pragma unroll
  for (int off = 32; off; off >>= 1) h += __shfl_xor(h, off, 64);
  if (lane == 0) red[wid] = h;

  float e = 0.f;
  for (int i = tid; i < 1152; i += 256) e += heter_part[i];
  #pragma unroll
  for (int off = 32; off; off >>= 1) e += __shfl_xor(e, off, 64);
  if (lane == 0) red[4 + wid] = e;

  __syncthreads();
  if (tid == 0) out[0] = (red[0] + red[1] + red[2] + red[3]) * (1.0f / 1536.0f);
  if (tid == 1) out[1] = (red[4] + red[5] + red[6] + red[7]) * (1.0f / 522240.0f);
}

extern "C" void kernel_launch(void* const* d_in, const int* in_sizes, int n_in,
                              void* d_out, int out_size, void* d_ws, size_t ws_size,
                              hipStream_t stream) {
  const float* x = (const float*)d_in[0];
  float* out = (float*)d_out;
  char* ws = (char*)d_ws;
  unsigned short* xb = (unsigned short*)(ws + XB_OFF);
  float* sq         = (float*)(ws + SQ_OFF);
  float* homo_part  = (float*)(ws + HOMO_OFF);
  float* heter_part = (float*)(ws + HETER_OFF);

  k_fused<<<2048, 256, 0, stream>>>(x, xb, sq, homo_part);
  k_heter<<<1152, 256, 0, stream>>>(xb, sq, heter_part);
  k_final<<<1, 256, 0, stream>>>(homo_part, heter_part, out);
}

// Round 11
// 38.356 us; speedup vs baseline: 3.5158x; 1.0020x over previous
//
#include <hip/hip_runtime.h>
#include <stdint.h>

// MetricLoss: B=1024, M=32, F=256, K_GRP=4
// out[0] = (1/1536) * sum_{same-group pairs i<j, m} ||x_i,m - x_j,m||^2
// out[1] = (1/522240) * sum_{g_i<g_j, m} relu(1 - ||x_i,m - x_j,m||^2)
//
// R11: k_heter = BK=32 double-buffered pipeline, ~36 KB LDS -> 4 blocks/CU
// (R8/R10 evidence: latency-bound, concurrency is the lever). Linear LDS
// layout: [128][32] bf16 is inherently bank-uniform for the b128 fragment
// read (R3 analysis) -> no swizzle, simpler staging. Counted vmcnt, never 0
// until the last step. No device-scope sync anywhere (R9 lesson).
//
// ws layout:
//   [0,        16 MiB)   : xb  bf16 [32][1024][256]
//   [16 MiB,  +128 KiB)  : sq  f32  [32][1024]
//   [+32 KiB]            : homo_part  f32 [8192]
//   [+4.5 KiB]           : heter_part f32 [1152]

typedef __attribute__((ext_vector_type(4))) float f32x4;
typedef __attribute__((ext_vector_type(8))) short bf16x8;

#define XB_OFF    0u
#define SQ_OFF    16777216u
#define HOMO_OFF  16908288u   // 8192 floats
#define HETER_OFF 16941056u   // 1152 floats

#define AS1 __attribute__((address_space(1)))
#define AS3 __attribute__((address_space(3)))

__device__ __forceinline__ void async16(const void* g, void* l) {
  __builtin_amdgcn_global_load_lds((const AS1 unsigned int*)(uintptr_t)g,
                                   (AS3 unsigned int*)(uintptr_t)l, 16, 0, 0);
}

__device__ __forceinline__ unsigned short f2bf(float f) {
  union { float f; unsigned u; } v; v.f = f;
  return (unsigned short)((v.u + 0x7fffu + ((v.u >> 16) & 1u)) >> 16);
}

// ---- Kernel 1 (fused convert + homo) — unchanged
__global__ __launch_bounds__(256) void k_fused(const float* __restrict__ x,
                                               unsigned short* __restrict__ xb,
                                               float* __restrict__ sq,
                                               float* __restrict__ homo_part) {
  const int task = blockIdx.x * 4 + (threadIdx.x >> 6);  // task = g*32 + m
  const int lane = threadIdx.x & 63;
  const int g = task >> 5;
  const int m = task & 31;

  const float* base = x + ((size_t)(g * 4) * 32 + m) * 256 + lane * 4;
  float4 v[4];
  float sqv[4];
  #pragma unroll
  for (int a = 0; a < 4; ++a) {
    v[a] = *(const float4*)(base + a * 8192);
    float s = v[a].x * v[a].x + v[a].y * v[a].y + v[a].z * v[a].z + v[a].w * v[a].w;
    #pragma unroll
    for (int off = 32; off; off >>= 1) s += __shfl_xor(s, off, 64);
    sqv[a] = s;
    const int i = g * 4 + a;
    if (lane == 0) sq[m * 1024 + i] = s;
    ushort4 o;
    o.x = f2bf(v[a].x); o.y = f2bf(v[a].y); o.z = f2bf(v[a].z); o.w = f2bf(v[a].w);
    *(ushort4*)(xb + ((size_t)(m * 1024 + i)) * 256 + lane * 4) = o;
  }
  const float sx = v[0].x + v[1].x + v[2].x + v[3].x;
  const float sy = v[0].y + v[1].y + v[2].y + v[3].y;
  const float sz = v[0].z + v[1].z + v[2].z + v[3].z;
  const float sw = v[0].w + v[1].w + v[2].w + v[3].w;
  float s = sx * sx + sy * sy + sz * sz + sw * sw;
  #pragma unroll
  for (int off = 32; off; off >>= 1) s += __shfl_xor(s, off, 64);
  if (lane == 0)
    homo_part[task] = 4.f * (sqv[0] + sqv[1] + sqv[2] + sqv[3]) - s;
}

// Stage one 8 KB panel-step (128 rows x 32 k) into an LDS buffer, LINEAR.
// 512 chunks of 16B; chunk ch -> row ch>>2, 16B-col ch&3. 2 loads/thread.
__device__ __forceinline__ void stage_panel(const unsigned short* __restrict__ X,
                                            int k0, unsigned short* buf, int tid) {
  #pragma unroll
  for (int i = 0; i < 2; ++i) {
    const int ch = i * 256 + tid;
    const int row = ch >> 2;
    const int c   = ch & 3;
    async16(X + (size_t)row * 256 + k0 + c * 8, (char*)buf + ch * 16);
  }
}

// ---- Kernel 2: heter loss, BK=32, double-buffered, 4 blocks/CU.
__global__ __launch_bounds__(256, 4) void k_heter(const unsigned short* __restrict__ xb,
                                                  const float* __restrict__ sq,
                                                  float* __restrict__ heter_part) {
  const int d = blockIdx.x;                  // 1152 = 8 * 144
  const int w = (d & 7) * 144 + (d >> 3);    // XCD chunk map (bijective)
  const int m = w / 36;
  int t0 = w - m * 36, r = 0;                // triangle decode: (r,c), c>=r
  while (t0 >= 8 - r) { t0 -= 8 - r; ++r; }
  const int cb = r + t0;
  const bool diag = (cb == r);

  __shared__ __align__(16) unsigned short A0[4096], A1[4096];  // 8 KB each
  __shared__ __align__(16) unsigned short B0[4096], B1[4096];
  __shared__ __align__(16) float sql[1024];                    // 4 KB sq row
  __shared__ float part[4];

  const int tid = threadIdx.x;
  const int lane = tid & 63;
  const int wid = tid >> 6;
  const int wr = wid >> 1, wc = wid & 1;     // 2x2 waves, each 64x64 output
  const int fr = lane & 15;
  const int kg = lane >> 4;

  const unsigned short* Xa = xb + ((size_t)m * 1024 + r  * 128) * 256;
  const unsigned short* Xb = xb + ((size_t)m * 1024 + cb * 128) * 256;

  // prologue: sq row + steps 0,1 of both panels (sql first -> drained by 1st wait)
  async16(sq + m * 1024 + tid * 4, (char*)sql + tid * 16);
  stage_panel(Xa, 0, A0, tid);
  if (!diag) stage_panel(Xb, 0, B0, tid);
  stage_panel(Xa, 32, A1, tid);
  if (!diag) stage_panel(Xb, 32, B1, tid);

  f32x4 acc[4][4] = {};

  #pragma unroll
  for (int s = 0; s < 8; ++s) {
    // counted wait: step-s landed; step-(s+1)(+2) loads stay in flight
    if (s < 7) {
      if (diag) asm volatile("s_waitcnt vmcnt(2)" ::: "memory");
      else      asm volatile("s_waitcnt vmcnt(4)" ::: "memory");
    } else {
      asm volatile("s_waitcnt vmcnt(0)" ::: "memory");
    }
    __builtin_amdgcn_s_barrier();
    asm volatile("" ::: "memory");

    const unsigned short* lA = (s & 1) ? A1 : A0;
    const unsigned short* lB = diag ? lA : ((s & 1) ? B1 : B0);
    bf16x8 af[4], bv[4];
    #pragma unroll
    for (int q = 0; q < 4; ++q) {
      const int ra = wr * 64 + q * 16 + fr;
      af[q] = *(const bf16x8*)(lA + ra * 32 + kg * 8);
      const int rb = wc * 64 + q * 16 + fr;
      bv[q] = *(const bf16x8*)(lB + rb * 32 + kg * 8);
    }
    #pragma unroll
    for (int ai = 0; ai < 4; ++ai)
      #pragma unroll
      for (int bj = 0; bj < 4; ++bj)
        acc[ai][bj] = __builtin_amdgcn_mfma_f32_16x16x32_bf16(af[ai], bv[bj],
                                                              acc[ai][bj], 0, 0, 0);

    asm volatile("" ::: "memory");
    __builtin_amdgcn_s_barrier();            // all waves done reading step-s bufs
    asm volatile("" ::: "memory");
    if (s + 2 < 8) {                         // refill freed buffers with step s+2
      stage_panel(Xa, (s + 2) * 32, (s & 1) ? A1 : A0, tid);
      if (!diag) stage_panel(Xb, (s + 2) * 32, (s & 1) ? B1 : B0, tid);
    }
  }

  // epilogue: relu(1 - (sq_i + sq_j - 2*dot)), strict group mask, reduce
  const int ibase = r  * 128 + wr * 64;
  const int jbase = cb * 128 + wc * 64;
  float sqi[4][4];
  #pragma unroll
  for (int ai = 0; ai < 4; ++ai)
    #pragma unroll
    for (int rg = 0; rg < 4; ++rg)
      sqi[ai][rg] = sql[ibase + ai * 16 + kg * 4 + rg];

  float local = 0.f;
  #pragma unroll
  for (int bj = 0; bj < 4; ++bj) {
    const int j = jbase + bj * 16 + fr;      // C/D: col = lane&15
    const float sqj = sql[j];
    const int gj = j >> 2;
    #pragma unroll
    for (int ai = 0; ai < 4; ++ai)
      #pragma unroll
      for (int rg = 0; rg < 4; ++rg) {
        const int i = ibase + ai * 16 + kg * 4 + rg;  // row = (lane>>4)*4 + reg
        const float dd = sqi[ai][rg] + sqj - 2.f * acc[ai][bj][rg];
        const float v = 1.f - dd;
        if (v > 0.f && gj > (i >> 2)) local += v;
      }
  }
  #pragma unroll
  for (int off = 32; off; off >>= 1) local += __shfl_xor(local, off, 64);
  if (lane == 0) part[wid] = local;
  __syncthreads();
  if (tid == 0) heter_part[w] = part[0] + part[1] + part[2] + part[3];
}

// ---- Kernel 3: final reduction of partials + scaling (single block)
__global__ __launch_bounds__(256) void k_final(const float* __restrict__ homo_part,
                                               const float* __restrict__ heter_part,
                                               float* __restrict__ out) {
  __shared__ float red[8];
  const int tid = threadIdx.x;
  const int lane = tid & 63;
  const int wid = tid >> 6;

  float h = 0.f;
  for (int i = tid; i < 8192; i += 256) h += homo_part[i];
  #pragma unroll
  for (int off = 32; off; off >>= 1) h += __shfl_xor(h, off, 64);
  if (lane == 0) red[wid] = h;

  float e = 0.f;
  for (int i = tid; i < 1152; i += 256) e += heter_part[i];
  #pragma unroll
  for (int off = 32; off; off >>= 1) e += __shfl_xor(e, off, 64);
  if (lane == 0) red[4 + wid] = e;

  __syncthreads();
  if (tid == 0) out[0] = (red[0] + red[1] + red[2] + red[3]) * (1.0f / 1536.0f);
  if (tid == 1) out[1] = (red[4] + red[5] + red[6] + red[7]) * (1.0f / 522240.0f);
}

extern "C" void kernel_launch(void* const* d_in, const int* in_sizes, int n_in,
                              void* d_out, int out_size, void* d_ws, size_t ws_size,
                              hipStream_t stream) {
  const float* x = (const float*)d_in[0];
  float* out = (float*)d_out;
  char* ws = (char*)d_ws;
  unsigned short* xb = (unsigned short*)(ws + XB_OFF);
  float* sq         = (float*)(ws + SQ_OFF);
  float* homo_part  = (float*)(ws + HOMO_OFF);
  float* heter_part = (float*)(ws + HETER_OFF);

  k_fused<<<2048, 256, 0, stream>>>(x, xb, sq, homo_part);
  k_heter<<<1152, 256, 0, stream>>>(xb, sq, heter_part);
  k_final<<<1, 256, 0, stream>>>(homo_part, heter_part, out);
}